// Round 1
// baseline (1495.546 us; speedup 1.0000x reference)
//
#include <hip/hip_runtime.h>

#define BB 2
#define NN 20000
#define EE 640000
#define SLICE 129   // per-thread LDS slice stride in words; odd -> bank-conflict-free

// Generic serial MLP layer: activations in per-thread LDS slice (rolled k-loop,
// runtime index OK in LDS), accumulators in registers (unrolled o-loop, static
// index). Weight/bias reads are wave-uniform -> scalar loads.
template<int K, int N, bool RELU>
__device__ __forceinline__ void layer_lds(const float* __restrict__ W,
                                          const float* __restrict__ Bv,
                                          float* __restrict__ sl) {
    float acc[N];
#pragma unroll
    for (int o = 0; o < N; ++o) acc[o] = Bv[o];
#pragma unroll 4
    for (int k = 0; k < K; ++k) {
        const float a = sl[k];
        const float* __restrict__ wr = W + k * N;
#pragma unroll
        for (int o = 0; o < N; ++o) acc[o] = __builtin_fmaf(a, wr[o], acc[o]);
    }
#pragma unroll
    for (int o = 0; o < N; ++o) sl[o] = RELU ? fmaxf(acc[o], 0.0f) : acc[o];
}

__global__ __launch_bounds__(64) void edge_kernel(
    const float* __restrict__ rel, const int* __restrict__ recv,
    const float* __restrict__ w0, const float* __restrict__ b0,
    const float* __restrict__ w1, const float* __restrict__ b1,
    const float* __restrict__ w2, const float* __restrict__ b2,
    const float* __restrict__ w3, const float* __restrict__ b3,
    const float* __restrict__ w4, const float* __restrict__ b4,
    float* __restrict__ agg) {
    extern __shared__ float lds[];
    float* sl = lds + threadIdx.x * SLICE;

    const long idx = (long)blockIdx.x * 64 + threadIdx.x;
    if (idx >= (long)BB * EE) return;
    const int b = (int)(idx / EE);
    const int e = (int)(idx % EE);

    // load rel[b][e][0:16] (64B-aligned) into the LDS slice
    const float4* rp = (const float4*)(rel + ((long)b * EE + e) * 16);
#pragma unroll
    for (int i = 0; i < 4; ++i) {
        float4 v = rp[i];
        sl[4 * i + 0] = v.x; sl[4 * i + 1] = v.y;
        sl[4 * i + 2] = v.z; sl[4 * i + 3] = v.w;
    }

    layer_lds<16, 128, true >(w0, b0, sl);
    layer_lds<128, 64, true >(w1, b1, sl);
    layer_lds<64, 32, true >(w2, b2, sl);
    layer_lds<32, 16, true >(w3, b3, sl);
    layer_lds<16, 16, false>(w4, b4, sl);

    float* dst = agg + ((long)b * NN + recv[e]) * 16;
#pragma unroll
    for (int j = 0; j < 16; ++j) atomicAdd(dst + j, sl[j]);
}

__global__ __launch_bounds__(64) void node_kernel(
    const float* __restrict__ dyn, const float* __restrict__ agg,
    const float* __restrict__ w0, const float* __restrict__ b0,
    const float* __restrict__ w1, const float* __restrict__ b1,
    const float* __restrict__ w2, const float* __restrict__ b2,
    const float* __restrict__ w3, const float* __restrict__ b3,
    const float* __restrict__ w4, const float* __restrict__ b4,
    float* __restrict__ out) {
    extern __shared__ float lds[];
    float* sl = lds + threadIdx.x * SLICE;

    const long idx = (long)blockIdx.x * 64 + threadIdx.x;
    if (idx >= (long)BB * NN) return;
    const int b = (int)(idx / NN);
    const int n = (int)(idx % NN);

    // concat(dyn[b][n][0:14], agg[b][n][0:16]) -> sl[0:30]
    const float2* dp = (const float2*)(dyn + ((long)b * NN + n) * 14);  // 8B-aligned
#pragma unroll
    for (int i = 0; i < 7; ++i) {
        float2 v = dp[i];
        sl[2 * i + 0] = v.x; sl[2 * i + 1] = v.y;
    }
    const float4* ap = (const float4*)(agg + ((long)b * NN + n) * 16);
#pragma unroll
    for (int i = 0; i < 4; ++i) {
        float4 v = ap[i];
        sl[14 + 4 * i + 0] = v.x; sl[14 + 4 * i + 1] = v.y;
        sl[14 + 4 * i + 2] = v.z; sl[14 + 4 * i + 3] = v.w;
    }

    layer_lds<30, 128, true >(w0, b0, sl);
    layer_lds<128, 64, true >(w1, b1, sl);
    layer_lds<64, 32, true >(w2, b2, sl);
    layer_lds<32, 16, true >(w3, b3, sl);
    layer_lds<16, 6, false>(w4, b4, sl);

    float* op = out + ((long)b * NN + n) * 6;
#pragma unroll
    for (int j = 0; j < 6; ++j) op[j] = sl[j];
}

extern "C" void kernel_launch(void* const* d_in, const int* in_sizes, int n_in,
                              void* d_out, int out_size, void* d_ws, size_t ws_size,
                              hipStream_t stream) {
    const float* dyn = (const float*)d_in[0];
    const float* rel = (const float*)d_in[1];
    const int* recv = (const int*)d_in[3];  // send (d_in[2]) is unused by reference

    const float* fw[5]; const float* fb[5]; const float* dw[5]; const float* db[5];
    for (int i = 0; i < 5; ++i) {
        fw[i] = (const float*)d_in[4 + 2 * i];
        fb[i] = (const float*)d_in[5 + 2 * i];
        dw[i] = (const float*)d_in[14 + 2 * i];
        db[i] = (const float*)d_in[15 + 2 * i];
    }

    float* agg = (float*)d_ws;  // [BB][NN][16] fp32 = 2.56 MB
    hipMemsetAsync(agg, 0, (size_t)BB * NN * 16 * sizeof(float), stream);

    const size_t lds_bytes = 64 * SLICE * sizeof(float);

    edge_kernel<<<(BB * EE + 63) / 64, 64, lds_bytes, stream>>>(
        rel, recv, fw[0], fb[0], fw[1], fb[1], fw[2], fb[2], fw[3], fb[3], fw[4], fb[4],
        agg);

    node_kernel<<<(BB * NN + 63) / 64, 64, lds_bytes, stream>>>(
        dyn, agg, dw[0], db[0], dw[1], db[1], dw[2], db[2], dw[3], db[3], dw[4], db[4],
        (float*)d_out);
}

// Round 3
// 1307.907 us; speedup vs baseline: 1.1435x; 1.1435x over previous
//
#include <hip/hip_runtime.h>

#define BB 2
#define NN 20000
#define EE 640000

// ---------------- per-layer tiled GEMM over a 64-edge LDS panel ----------------
// A: LDS [K][64] (k-major), Bout: LDS [N][64], W: global [K][N], Bv: global [N].
// 256 threads: row = tid%16 owns 4 edges (e0=row*4), col = tid/16 owns TO outputs.
// Weights: depth-2 prefetch from global (L1-resident). Accs fully static in regs.

template<int TO>
__device__ __forceinline__ void loadrow(const float* __restrict__ p, float* w) {
    if constexpr (TO == 1) {
        w[0] = p[0];
    } else if constexpr (TO == 2) {
        float2 v = *(const float2*)p; w[0] = v.x; w[1] = v.y;
    } else if constexpr (TO == 4) {
        float4 v = *(const float4*)p;
        w[0] = v.x; w[1] = v.y; w[2] = v.z; w[3] = v.w;
    } else {
        float4 v0 = *(const float4*)p; float4 v1 = *(const float4*)(p + 4);
        w[0] = v0.x; w[1] = v0.y; w[2] = v0.z; w[3] = v0.w;
        w[4] = v1.x; w[5] = v1.y; w[6] = v1.z; w[7] = v1.w;
    }
}

template<int K, int N, int TO, bool RELU>
__device__ __forceinline__ void gemm_layer(const float* __restrict__ W,
                                           const float* __restrict__ Bv,
                                           const float* __restrict__ A,
                                           float* __restrict__ Bout,
                                           int row, int col) {
    static_assert(N % TO == 0 && K % 2 == 0, "");
    constexpr int COLS = N / TO;
    if (COLS < 16 && col >= COLS) return;  // idle lanes still hit caller's barrier

    const int e0 = row * 4;
    const int o0 = col * TO;

    float acc[4][TO];
#pragma unroll
    for (int j = 0; j < TO; ++j) {
        const float bj = Bv[o0 + j];
        acc[0][j] = bj; acc[1][j] = bj; acc[2][j] = bj; acc[3][j] = bj;
    }

    float w0[TO], w1[TO];
    loadrow<TO>(W + 0 * N + o0, w0);
    loadrow<TO>(W + 1 * N + o0, w1);

    for (int k = 0; k < K; k += 2) {
        const int kn = (k + 2 < K) ? (k + 2) : 0;   // dummy reload of row 0/1 on last iter
        float wn0[TO], wn1[TO];
        loadrow<TO>(W + kn * N + o0, wn0);
        loadrow<TO>(W + (kn + 1) * N + o0, wn1);

        const float4 a0 = *(const float4*)(A + k * 64 + e0);
        const float4 a1 = *(const float4*)(A + (k + 1) * 64 + e0);
#pragma unroll
        for (int j = 0; j < TO; ++j) {
            acc[0][j] = __builtin_fmaf(a0.x, w0[j], acc[0][j]);
            acc[1][j] = __builtin_fmaf(a0.y, w0[j], acc[1][j]);
            acc[2][j] = __builtin_fmaf(a0.z, w0[j], acc[2][j]);
            acc[3][j] = __builtin_fmaf(a0.w, w0[j], acc[3][j]);
        }
#pragma unroll
        for (int j = 0; j < TO; ++j) {
            acc[0][j] = __builtin_fmaf(a1.x, w1[j], acc[0][j]);
            acc[1][j] = __builtin_fmaf(a1.y, w1[j], acc[1][j]);
            acc[2][j] = __builtin_fmaf(a1.z, w1[j], acc[2][j]);
            acc[3][j] = __builtin_fmaf(a1.w, w1[j], acc[3][j]);
        }
#pragma unroll
        for (int j = 0; j < TO; ++j) { w0[j] = wn0[j]; w1[j] = wn1[j]; }
    }

#pragma unroll
    for (int j = 0; j < TO; ++j) {
        float4 v;
        v.x = RELU ? fmaxf(acc[0][j], 0.f) : acc[0][j];
        v.y = RELU ? fmaxf(acc[1][j], 0.f) : acc[1][j];
        v.z = RELU ? fmaxf(acc[2][j], 0.f) : acc[2][j];
        v.w = RELU ? fmaxf(acc[3][j], 0.f) : acc[3][j];
        *(float4*)(Bout + (o0 + j) * 64 + e0) = v;
    }
}

// ---------------- edge kernel: frel MLP over 64-edge panels + atomic scatter ----------------
__global__ __launch_bounds__(256) void edge_kernel(
    const float* __restrict__ rel, const int* __restrict__ recv,
    const float* __restrict__ w0, const float* __restrict__ b0,
    const float* __restrict__ w1, const float* __restrict__ b1,
    const float* __restrict__ w2, const float* __restrict__ b2,
    const float* __restrict__ w3, const float* __restrict__ b3,
    const float* __restrict__ w4, const float* __restrict__ b4,
    float* __restrict__ agg) {
    __shared__ float X[64 * 64];    // 16 KB
    __shared__ float Y[128 * 64];   // 32 KB
    const int tid = threadIdx.x;
    const int row = tid & 15, col = tid >> 4;
    const int b = blockIdx.x / (EE / 64);
    const int eg0 = (blockIdx.x % (EE / 64)) * 64;

    // stage rel[b][eg0+e][0:16] -> X[16][64] (k-major)
    {
        const int e = tid >> 2, q = tid & 3;
        const float4 v = *(const float4*)(rel + ((long)b * EE + eg0 + e) * 16 + q * 4);
        X[(4 * q + 0) * 64 + e] = v.x;
        X[(4 * q + 1) * 64 + e] = v.y;
        X[(4 * q + 2) * 64 + e] = v.z;
        X[(4 * q + 3) * 64 + e] = v.w;
    }
    __syncthreads();
    gemm_layer<16, 128, 8, true >(w0, b0, X, Y, row, col); __syncthreads();
    gemm_layer<128, 64, 4, true >(w1, b1, Y, X, row, col); __syncthreads();
    gemm_layer<64, 32, 2, true >(w2, b2, X, Y, row, col); __syncthreads();
    gemm_layer<32, 16, 1, true >(w3, b3, Y, X, row, col); __syncthreads();
    gemm_layer<16, 16, 1, false>(w4, b4, X, Y, row, col); __syncthreads();

    // scatter: 16 channels x 64 edges, 4 atomics per thread
    const int e = tid & 63;
    const int c0 = (tid >> 6) * 4;
    const int node = recv[eg0 + e];
    float* dst = agg + ((long)b * NN + node) * 16;
#pragma unroll
    for (int j = 0; j < 4; ++j)
        atomicAdd(dst + c0 + j, Y[(c0 + j) * 64 + e]);
}

// ---------------- node kernel: fdyn MLP over 64-node panels ----------------
__global__ __launch_bounds__(256) void node_kernel(
    const float* __restrict__ dyn, const float* __restrict__ agg,
    const float* __restrict__ w0, const float* __restrict__ b0,
    const float* __restrict__ w1, const float* __restrict__ b1,
    const float* __restrict__ w2, const float* __restrict__ b2,
    const float* __restrict__ w3, const float* __restrict__ b3,
    const float* __restrict__ w4, const float* __restrict__ b4,
    float* __restrict__ out) {
    __shared__ float X[64 * 64];
    __shared__ float Y[128 * 64];
    const int tid = threadIdx.x;
    const int row = tid & 15, col = tid >> 4;
    constexpr int NBLK = (NN + 63) / 64;   // 313
    const int b = blockIdx.x / NBLK;
    const int ng0 = (blockIdx.x % NBLK) * 64;

    // stage concat(dyn[14], agg[16]) -> X[30][64], zero-fill past NN
    if (tid < 64) {
        const int n = ng0 + tid;
        if (n < NN) {
            const float2* dp = (const float2*)(dyn + ((long)b * NN + n) * 14);
#pragma unroll
            for (int i = 0; i < 7; ++i) {
                float2 v = dp[i];
                X[(2 * i + 0) * 64 + tid] = v.x;
                X[(2 * i + 1) * 64 + tid] = v.y;
            }
        } else {
#pragma unroll
            for (int i = 0; i < 14; ++i) X[i * 64 + tid] = 0.f;
        }
    } else if (tid < 128) {
        const int t = tid - 64, n = ng0 + t;
        if (n < NN) {
            const float4* ap = (const float4*)(agg + ((long)b * NN + n) * 16);
#pragma unroll
            for (int i = 0; i < 4; ++i) {
                float4 v = ap[i];
                X[(14 + 4 * i + 0) * 64 + t] = v.x;
                X[(14 + 4 * i + 1) * 64 + t] = v.y;
                X[(14 + 4 * i + 2) * 64 + t] = v.z;
                X[(14 + 4 * i + 3) * 64 + t] = v.w;
            }
        } else {
#pragma unroll
            for (int i = 0; i < 16; ++i) X[(14 + i) * 64 + t] = 0.f;
        }
    }
    __syncthreads();
    gemm_layer<30, 128, 8, true >(w0, b0, X, Y, row, col); __syncthreads();
    gemm_layer<128, 64, 4, true >(w1, b1, Y, X, row, col); __syncthreads();
    gemm_layer<64, 32, 2, true >(w2, b2, X, Y, row, col); __syncthreads();
    gemm_layer<32, 16, 1, true >(w3, b3, Y, X, row, col); __syncthreads();
    gemm_layer<16, 6, 1, false>(w4, b4, X, Y, row, col); __syncthreads();

    // out[b][n][0:6] from Y[6][64], 3 float2 columns
    if (tid < 192) {
        const int n = tid & 63, cp = tid >> 6;  // cp = 0..2
        const int gn = ng0 + n;
        if (gn < NN) {
            float2 v;
            v.x = Y[(2 * cp + 0) * 64 + n];
            v.y = Y[(2 * cp + 1) * 64 + n];
            *(float2*)(out + ((long)b * NN + gn) * 6 + 2 * cp) = v;
        }
    }
}

extern "C" void kernel_launch(void* const* d_in, const int* in_sizes, int n_in,
                              void* d_out, int out_size, void* d_ws, size_t ws_size,
                              hipStream_t stream) {
    const float* dyn = (const float*)d_in[0];
    const float* rel = (const float*)d_in[1];
    const int* recv = (const int*)d_in[3];  // send (d_in[2]) unused by reference

    const float* fw[5]; const float* fb[5]; const float* dw[5]; const float* db[5];
    for (int i = 0; i < 5; ++i) {
        fw[i] = (const float*)d_in[4 + 2 * i];
        fb[i] = (const float*)d_in[5 + 2 * i];
        dw[i] = (const float*)d_in[14 + 2 * i];
        db[i] = (const float*)d_in[15 + 2 * i];
    }

    float* agg = (float*)d_ws;  // [BB][NN][16] fp32 = 2.56 MB
    hipMemsetAsync(agg, 0, (size_t)BB * NN * 16 * sizeof(float), stream);

    edge_kernel<<<BB * (EE / 64), 256, 0, stream>>>(
        rel, recv, fw[0], fb[0], fw[1], fb[1], fw[2], fb[2], fw[3], fb[3], fw[4], fb[4],
        agg);

    constexpr int NBLK = (NN + 63) / 64;
    node_kernel<<<BB * NBLK, 256, 0, stream>>>(
        dyn, agg, dw[0], db[0], dw[1], db[1], dw[2], db[2], dw[3], db[3], dw[4], db[4],
        (float*)d_out);
}

// Round 6
// 540.163 us; speedup vs baseline: 2.7687x; 2.4213x over previous
//
#include <hip/hip_runtime.h>

#define BB 2
#define NN 20000
#define EE 640000

using short8 = __attribute__((ext_vector_type(8))) short;
using f32x4  = __attribute__((ext_vector_type(4))) float;
typedef unsigned int uint;

// ---------- bf16 split helpers (RNE) ----------
__device__ __forceinline__ uint bf16_rne(float f) {
    uint u = __float_as_uint(f);
    return (u + 0x7fffu + ((u >> 16) & 1u)) >> 16;
}
__device__ __forceinline__ float bf16_f(uint h) { return __uint_as_float(h << 16); }
__device__ __forceinline__ void split2(float x, float y, uint& hi, uint& lo) {
    uint hx = bf16_rne(x), hy = bf16_rne(y);
    uint lx = bf16_rne(x - bf16_f(hx)), ly = bf16_rne(y - bf16_f(hy));
    hi = hx | (hy << 16);
    lo = lx | (ly << 16);
}

// ---------- B-fragment load from swizzled LDS ----------
// X stored [16 rows][K ch] bf16, byte-swizzle: off ^= (row&emask)<<4.
template<int KT>
__device__ __forceinline__ void loadB(const char* H, const char* L, int rowb, int emask,
                                      int li, int q, short8* bh, short8* bl) {
    const int sw = (li & emask) << 4;
    const char* rh = H + li * rowb;
    const char* rl = L + li * rowb;
#pragma unroll
    for (int kt = 0; kt < KT; ++kt) {
        const int off = (kt * 64 + q * 16) ^ sw;
        bh[kt] = *(const short8*)(rh + off);
        bl[kt] = *(const short8*)(rl + off);
    }
}

#define MFMA16(a, b, c) __builtin_amdgcn_mfma_f32_16x16x32_bf16(a, b, c, 0, 0, 0)

// D[ch][edge] = sum_k W[k][ch] * X[edge][k]  (swapped operands: A=W^T frags, B=X^T frags)
// bf16x4: hi@hi + hi@lo + lo@hi + lo@lo.
template<int KT, int MT, bool BIAS4>
__device__ __forceinline__ void do_layer(const char* __restrict__ wf, const float* __restrict__ bias,
                                         const short8* bh, const short8* bl,
                                         int lane, f32x4* acc, int nReal) {
    const int q = lane >> 4;
#pragma unroll
    for (int mt = 0; mt < MT; ++mt) {
        if constexpr (BIAS4) {
            const float4 bv = *(const float4*)(bias + mt * 16 + q * 4);
            acc[mt][0] = bv.x; acc[mt][1] = bv.y; acc[mt][2] = bv.z; acc[mt][3] = bv.w;
        } else {
#pragma unroll
            for (int r = 0; r < 4; ++r) {
                const int ch = mt * 16 + q * 4 + r;
                acc[mt][r] = (ch < nReal) ? bias[ch] : 0.0f;
            }
        }
    }
#pragma unroll
    for (int kt = 0; kt < KT; ++kt) {
        short8 wh[MT], wl[MT];
#pragma unroll
        for (int mt = 0; mt < MT; ++mt) {
            const char* p = wf + (size_t)(mt * KT + kt) * 2048 + lane * 16;
            wh[mt] = *(const short8*)p;
            wl[mt] = *(const short8*)(p + 1024);
        }
#pragma unroll
        for (int mt = 0; mt < MT; ++mt) acc[mt] = MFMA16(wh[mt], bh[kt], acc[mt]);
#pragma unroll
        for (int mt = 0; mt < MT; ++mt) acc[mt] = MFMA16(wh[mt], bl[kt], acc[mt]);
#pragma unroll
        for (int mt = 0; mt < MT; ++mt) acc[mt] = MFMA16(wl[mt], bh[kt], acc[mt]);
#pragma unroll
        for (int mt = 0; mt < MT; ++mt) acc[mt] = MFMA16(wl[mt], bl[kt], acc[mt]);
    }
}

// ReLU + hi/lo split + packed b32 writes into swizzled LDS (hidden layers only).
template<int MT>
__device__ __forceinline__ void store_acts(char* H, char* L, int rowb, int emask,
                                           int lane, const f32x4* acc) {
    const int li = lane & 15, q = lane >> 4;
    const int sw = (li & emask) << 4;
    char* rh = H + li * rowb;
    char* rl = L + li * rowb;
#pragma unroll
    for (int mt = 0; mt < MT; ++mt) {
        const float v0 = fmaxf(acc[mt][0], 0.f), v1 = fmaxf(acc[mt][1], 0.f);
        const float v2 = fmaxf(acc[mt][2], 0.f), v3 = fmaxf(acc[mt][3], 0.f);
        uint h01, l01, h23, l23;
        split2(v0, v1, h01, l01);
        split2(v2, v3, h23, l23);
        const int off = (mt * 32 + q * 8) ^ sw;
        *(uint*)(rh + off) = h01; *(uint*)(rh + off + 4) = h23;
        *(uint*)(rl + off) = l01; *(uint*)(rl + off + 4) = l23;
    }
}

#define DECL_LDS \
    __shared__ __align__(16) char XH0[16 * 64];  __shared__ __align__(16) char XL0[16 * 64];  \
    __shared__ __align__(16) char XH1[16 * 256]; __shared__ __align__(16) char XL1[16 * 256]; \
    __shared__ __align__(16) char XH2[16 * 128]; __shared__ __align__(16) char XL2[16 * 128];

// ---------------- edge MLP: 16-edge panel per wave, no barriers ----------------
template<int CSR>
__global__ __launch_bounds__(64, 3) void edge_mlp(
    const float* __restrict__ rel, const int* __restrict__ recv, const int* __restrict__ posOf,
    const char* __restrict__ wfrag,
    const float* __restrict__ b0, const float* __restrict__ b1, const float* __restrict__ b2,
    const float* __restrict__ b3, const float* __restrict__ b4,
    float* __restrict__ outp /* msg (CSR) or agg (atomic) */) {
    DECL_LDS
    const int lane = threadIdx.x;
    const int li = lane & 15, q = lane >> 4;
    const int b = blockIdx.x / (EE / 16);
    const int eg0 = (blockIdx.x % (EE / 16)) * 16;

    {   // stage rel -> X0 ([16 edges][32 ch], ch16..31 zero)
        const int e = lane >> 2, c = lane & 3;
        const float4 v = *(const float4*)(rel + ((size_t)b * EE + eg0 + e) * 16 + c * 4);
        uint h01, l01, h23, l23;
        split2(v.x, v.y, h01, l01);
        split2(v.z, v.w, h23, l23);
        const int sw = (e & 3) << 4;
        char* rh = XH0 + e * 64; char* rl = XL0 + e * 64;
        const int o = (c * 8) ^ sw;
        *(uint*)(rh + o) = h01; *(uint*)(rh + o + 4) = h23;
        *(uint*)(rl + o) = l01; *(uint*)(rl + o + 4) = l23;
        const int oz = (32 + c * 8) ^ sw;
        *(uint*)(rh + oz) = 0; *(uint*)(rh + oz + 4) = 0;
        *(uint*)(rl + oz) = 0; *(uint*)(rl + oz + 4) = 0;
    }
    short8 bh[4], bl[4];
    f32x4 a8[8], a4[4], a2[2], a1[1];

    loadB<1>(XH0, XL0, 64, 3, li, q, bh, bl);
    do_layer<1, 8, true>(wfrag + 0, b0, bh, bl, lane, a8, 128);
    store_acts<8>(XH1, XL1, 256, 7, lane, a8);

    loadB<4>(XH1, XL1, 256, 7, li, q, bh, bl);
    do_layer<4, 4, true>(wfrag + 16384, b1, bh, bl, lane, a4, 64);
    store_acts<4>(XH2, XL2, 128, 7, lane, a4);

    loadB<2>(XH2, XL2, 128, 7, li, q, bh, bl);
    do_layer<2, 2, true>(wfrag + 49152, b2, bh, bl, lane, a2, 32);
    store_acts<2>(XH0, XL0, 64, 3, lane, a2);

    loadB<1>(XH0, XL0, 64, 3, li, q, bh, bl);
    do_layer<1, 1, true>(wfrag + 57344, b3, bh, bl, lane, a1, 16);
    store_acts<1>(XH2, XL2, 128, 7, lane, a1);
    {   // zero-pad ch16..31 of the K=32 container in X2
        const int sw = (li & 7) << 4;
        const int oz = (32 + q * 8) ^ sw;
        *(uint*)(XH2 + li * 128 + oz) = 0; *(uint*)(XH2 + li * 128 + oz + 4) = 0;
        *(uint*)(XL2 + li * 128 + oz) = 0; *(uint*)(XL2 + li * 128 + oz + 4) = 0;
    }
    loadB<1>(XH2, XL2, 128, 7, li, q, bh, bl);
    do_layer<1, 1, true>(wfrag + 59392, b4, bh, bl, lane, a1, 16);

    if (CSR) {
        const int pos = posOf[eg0 + li];
        float4 v;
        v.x = a1[0][0]; v.y = a1[0][1]; v.z = a1[0][2]; v.w = a1[0][3];
        *(float4*)(outp + ((size_t)b * EE + pos) * 16 + q * 4) = v;
    } else {
        const int nd = recv[eg0 + li];
        float* dst = outp + ((size_t)b * NN + nd) * 16 + q * 4;
        atomicAdd(dst + 0, a1[0][0]); atomicAdd(dst + 1, a1[0][1]);
        atomicAdd(dst + 2, a1[0][2]); atomicAdd(dst + 3, a1[0][3]);
    }
}

// ---------------- node MLP: 16-node panel per wave ----------------
__global__ __launch_bounds__(64, 3) void node_mlp(
    const float* __restrict__ dyn, const float* __restrict__ agg,
    const char* __restrict__ wfrag,
    const float* __restrict__ b0, const float* __restrict__ b1, const float* __restrict__ b2,
    const float* __restrict__ b3, const float* __restrict__ b4,
    float* __restrict__ out) {
    DECL_LDS
    const int lane = threadIdx.x;
    const int li = lane & 15, q = lane >> 4;
    const int b = blockIdx.x / (NN / 16);
    const int ng0 = (blockIdx.x % (NN / 16)) * 16;

    {   // stage concat(dyn[14], agg[16]) -> X0 [16 nodes][32 ch], ch30..31 zero
        const int n = lane >> 2, p = lane & 3;
        const size_t dbase = ((size_t)b * NN + ng0 + n) * 14;
        const size_t abase = ((size_t)b * NN + ng0 + n) * 16;
        float qa0, qa1, qa2, qa3, qb0, qb1, qb2, qb3;
        if (p < 3) {
            const float2 u = *(const float2*)(dyn + dbase + 4 * p);
            const float2 w = *(const float2*)(dyn + dbase + 4 * p + 2);
            qa0 = u.x; qa1 = u.y; qa2 = w.x; qa3 = w.y;
            const float2 g0 = *(const float2*)(agg + abase + 2 + 4 * p);
            const float2 g1 = *(const float2*)(agg + abase + 4 + 4 * p);
            qb0 = g0.x; qb1 = g0.y; qb2 = g1.x; qb3 = g1.y;
        } else {
            const float2 u = *(const float2*)(dyn + dbase + 12);
            const float2 g = *(const float2*)(agg + abase + 0);
            qa0 = u.x; qa1 = u.y; qa2 = g.x; qa3 = g.y;
            const float2 g2 = *(const float2*)(agg + abase + 14);
            qb0 = g2.x; qb1 = g2.y; qb2 = 0.f; qb3 = 0.f;
        }
        const int sw = (n & 3) << 4;
        char* rh = XH0 + n * 64; char* rl = XL0 + n * 64;
        uint h01, l01, h23, l23;
        split2(qa0, qa1, h01, l01);
        split2(qa2, qa3, h23, l23);
        const int o = (p * 8) ^ sw;
        *(uint*)(rh + o) = h01; *(uint*)(rh + o + 4) = h23;
        *(uint*)(rl + o) = l01; *(uint*)(rl + o + 4) = l23;
        split2(qb0, qb1, h01, l01);
        split2(qb2, qb3, h23, l23);
        const int o2 = (32 + p * 8) ^ sw;
        *(uint*)(rh + o2) = h01; *(uint*)(rh + o2 + 4) = h23;
        *(uint*)(rl + o2) = l01; *(uint*)(rl + o2 + 4) = l23;
    }
    short8 bh[4], bl[4];
    f32x4 a8[8], a4[4], a2[2], a1[1];

    loadB<1>(XH0, XL0, 64, 3, li, q, bh, bl);
    do_layer<1, 8, true>(wfrag + 61440, b0, bh, bl, lane, a8, 128);
    store_acts<8>(XH1, XL1, 256, 7, lane, a8);

    loadB<4>(XH1, XL1, 256, 7, li, q, bh, bl);
    do_layer<4, 4, true>(wfrag + 77824, b1, bh, bl, lane, a4, 64);
    store_acts<4>(XH2, XL2, 128, 7, lane, a4);

    loadB<2>(XH2, XL2, 128, 7, li, q, bh, bl);
    do_layer<2, 2, true>(wfrag + 110592, b2, bh, bl, lane, a2, 32);
    store_acts<2>(XH0, XL0, 64, 3, lane, a2);

    loadB<1>(XH0, XL0, 64, 3, li, q, bh, bl);
    do_layer<1, 1, true>(wfrag + 118784, b3, bh, bl, lane, a1, 16);
    store_acts<1>(XH2, XL2, 128, 7, lane, a1);
    {
        const int sw = (li & 7) << 4;
        const int oz = (32 + q * 8) ^ sw;
        *(uint*)(XH2 + li * 128 + oz) = 0; *(uint*)(XH2 + li * 128 + oz + 4) = 0;
        *(uint*)(XL2 + li * 128 + oz) = 0; *(uint*)(XL2 + li * 128 + oz + 4) = 0;
    }
    loadB<1>(XH2, XL2, 128, 7, li, q, bh, bl);
    do_layer<1, 1, false>(wfrag + 120832, b4, bh, bl, lane, a1, 6);

    const int gn = ng0 + li;
#pragma unroll
    for (int r = 0; r < 4; ++r) {
        const int ch = q * 4 + r;
        if (ch < 6) out[((size_t)b * NN + gn) * 6 + ch] = a1[0][r];
    }
}

// ---------------- weight prep: pack hi/lo bf16 A-fragments ----------------
__global__ __launch_bounds__(64) void wprep(
    const float* w0f, const float* w1f, const float* w2f, const float* w3f, const float* w4f,
    const float* w0d, const float* w1d, const float* w2d, const float* w3d, const float* w4d,
    char* __restrict__ wfrag) {
    const int bid = blockIdx.x;  // 0..59
    const int lane = threadIdx.x;
    const int net = bid / 30;
    const int r = bid % 30;
    int l, base;
    if (r < 8)       { l = 0; base = 0; }
    else if (r < 24) { l = 1; base = 8; }
    else if (r < 28) { l = 2; base = 24; }
    else if (r < 29) { l = 3; base = 28; }
    else             { l = 4; base = 29; }
    const int KTs[5] = {1, 4, 2, 1, 1};
    const int Krf[5] = {16, 128, 64, 32, 16};
    const int Krd[5] = {30, 128, 64, 32, 16};
    const int Ncf[5] = {128, 64, 32, 16, 16};
    const int Ncd[5] = {128, 64, 32, 16, 6};
    const float* Wf[5] = {w0f, w1f, w2f, w3f, w4f};
    const float* Wd[5] = {w0d, w1d, w2d, w3d, w4d};
    const int KT = KTs[l];
    const int idx = r - base;
    const int mt = idx / KT, kt = idx % KT;
    const int Kreal = net ? Krd[l] : Krf[l];
    const int Ncol  = net ? Ncd[l] : Ncf[l];
    const float* W  = net ? Wd[l] : Wf[l];
    const int ch = mt * 16 + (lane & 15);
    uint hi[4], lo[4];
#pragma unroll
    for (int t = 0; t < 4; ++t) {
        float x = 0.f, y = 0.f;
        const int k0 = kt * 32 + (lane >> 4) * 8 + 2 * t;
        if (k0 < Kreal && ch < Ncol) x = W[(size_t)k0 * Ncol + ch];
        if (k0 + 1 < Kreal && ch < Ncol) y = W[(size_t)(k0 + 1) * Ncol + ch];
        split2(x, y, hi[t], lo[t]);
    }
    uint4 H; H.x = hi[0]; H.y = hi[1]; H.z = hi[2]; H.w = hi[3];
    uint4 L; L.x = lo[0]; L.y = lo[1]; L.z = lo[2]; L.w = lo[3];
    *(uint4*)(wfrag + (size_t)bid * 2048 + lane * 16) = H;
    *(uint4*)(wfrag + (size_t)bid * 2048 + 1024 + lane * 16) = L;
}

// ---------------- CSR build + gather ----------------
__global__ void count_k(const int* __restrict__ recv, int* __restrict__ counts) {
    const int e = blockIdx.x * 256 + threadIdx.x;
    if (e < EE) atomicAdd(&counts[recv[e]], 1);
}

__global__ __launch_bounds__(1024) void scan_k(const int* __restrict__ counts,
                                               int* __restrict__ start, int* __restrict__ cursor) {
    __shared__ int part[1024];
    const int t = threadIdx.x;
    const int lo = t * 20, hi = lo + 20 < NN ? lo + 20 : NN;
    int s = 0;
    for (int i = lo; i < hi; ++i) s += counts[i];
    part[t] = s;
    __syncthreads();
    for (int d = 1; d < 1024; d <<= 1) {
        int v = 0;
        if (t >= d) v = part[t - d];
        __syncthreads();
        part[t] += v;
        __syncthreads();
    }
    int run = t ? part[t - 1] : 0;
    for (int i = lo; i < hi; ++i) { start[i] = run; cursor[i] = run; run += counts[i]; }
    if (t == 0) start[NN] = EE;
}

__global__ void fill_k(const int* __restrict__ recv, int* __restrict__ cursor,
                       int* __restrict__ posOf) {
    const int e = blockIdx.x * 256 + threadIdx.x;
    if (e < EE) posOf[e] = atomicAdd(&cursor[recv[e]], 1);
}

__global__ void gather_k(const float* __restrict__ msg, const int* __restrict__ start,
                         float* __restrict__ agg) {
    const int t = blockIdx.x * 256 + threadIdx.x;  // (b*NN+n)*4 + oq
    if (t >= BB * NN * 4) return;
    const int oq = t & 3;
    const int bn = t >> 2;
    const int n = bn % NN, b = bn / NN;
    const int s = start[n], e = start[n + 1];
    float4 S; S.x = 0.f; S.y = 0.f; S.z = 0.f; S.w = 0.f;
    for (int i = s; i < e; ++i) {
        const float4 v = *(const float4*)(msg + ((size_t)b * EE + i) * 16 + oq * 4);
        S.x += v.x; S.y += v.y; S.z += v.z; S.w += v.w;
    }
    *(float4*)(agg + (size_t)bn * 16 + oq * 4) = S;
}

extern "C" void kernel_launch(void* const* d_in, const int* in_sizes, int n_in,
                              void* d_out, int out_size, void* d_ws, size_t ws_size,
                              hipStream_t stream) {
    const float* dyn = (const float*)d_in[0];
    const float* rel = (const float*)d_in[1];
    const int* recv = (const int*)d_in[3];  // send (d_in[2]) unused by reference

    const float* fw[5]; const float* fb[5]; const float* dw[5]; const float* db[5];
    for (int i = 0; i < 5; ++i) {
        fw[i] = (const float*)d_in[4 + 2 * i];
        fb[i] = (const float*)d_in[5 + 2 * i];
        dw[i] = (const float*)d_in[14 + 2 * i];
        db[i] = (const float*)d_in[15 + 2 * i];
    }

    char* ws = (char*)d_ws;
    char* wfrag = ws;  // 122880 B used, padded to 131072
    const size_t MSG_OFF = 131072;
    const size_t MSG_SZ = (size_t)BB * EE * 16 * 4;          // 81,920,000
    const size_t POS_OFF = MSG_OFF + MSG_SZ;                 // 82,051,072
    const size_t CNT_OFF = POS_OFF + (size_t)EE * 4;         // 84,611,072
    const size_t CUR_OFF = CNT_OFF + (size_t)NN * 4;         // 84,691,072
    const size_t STA_OFF = CUR_OFF + (size_t)NN * 4;         // 84,771,072
    const size_t AGG_OFF_CSR = STA_OFF + 80128;              // 84,851,200 (16B aligned)
    const size_t NEED = AGG_OFF_CSR + (size_t)BB * NN * 16 * 4;  // 87,411,200
    const bool csr = ws_size >= NEED;

    wprep<<<60, 64, 0, stream>>>(fw[0], fw[1], fw[2], fw[3], fw[4],
                                 dw[0], dw[1], dw[2], dw[3], dw[4], wfrag);

    float* agg;
    if (csr) {
        float* msg = (float*)(ws + MSG_OFF);
        int* posOf = (int*)(ws + POS_OFF);
        int* counts = (int*)(ws + CNT_OFF);
        int* cursor = (int*)(ws + CUR_OFF);
        int* start = (int*)(ws + STA_OFF);
        agg = (float*)(ws + AGG_OFF_CSR);

        hipMemsetAsync(counts, 0, (size_t)NN * 4, stream);
        count_k<<<(EE + 255) / 256, 256, 0, stream>>>(recv, counts);
        scan_k<<<1, 1024, 0, stream>>>(counts, start, cursor);
        fill_k<<<(EE + 255) / 256, 256, 0, stream>>>(recv, cursor, posOf);
        edge_mlp<1><<<BB * (EE / 16), 64, 0, stream>>>(
            rel, recv, posOf, wfrag, fb[0], fb[1], fb[2], fb[3], fb[4], msg);
        gather_k<<<(BB * NN * 4 + 255) / 256, 256, 0, stream>>>(msg, start, agg);
    } else {
        agg = (float*)(ws + MSG_OFF);
        hipMemsetAsync(agg, 0, (size_t)BB * NN * 16 * 4, stream);
        edge_mlp<0><<<BB * (EE / 16), 64, 0, stream>>>(
            rel, recv, nullptr, wfrag, fb[0], fb[1], fb[2], fb[3], fb[4], agg);
    }

    node_mlp<<<BB * (NN / 16), 64, 0, stream>>>(
        dyn, agg, wfrag, db[0], db[1], db[2], db[3], db[4], (float*)d_out);
}

// Round 8
// 523.159 us; speedup vs baseline: 2.8587x; 1.0325x over previous
//
#include <hip/hip_runtime.h>

#define BB 2
#define NN 20000
#define EE 640000

using short8 = __attribute__((ext_vector_type(8))) short;
using f32x4  = __attribute__((ext_vector_type(4))) float;
typedef unsigned int uint;

// ---------- bf16 split helpers (RNE) ----------
__device__ __forceinline__ uint bf16_rne(float f) {
    uint u = __float_as_uint(f);
    return (u + 0x7fffu + ((u >> 16) & 1u)) >> 16;
}
__device__ __forceinline__ float bf16_f(uint h) { return __uint_as_float(h << 16); }
__device__ __forceinline__ void split2(float x, float y, uint& hi, uint& lo) {
    uint hx = bf16_rne(x), hy = bf16_rne(y);
    uint lx = bf16_rne(x - bf16_f(hx)), ly = bf16_rne(y - bf16_f(hy));
    hi = hx | (hy << 16);
    lo = lx | (ly << 16);
}

// ---------- B-fragment load from swizzled LDS ----------
template<int KT>
__device__ __forceinline__ void loadB(const char* H, const char* L, int rowb, int emask,
                                      int li, int q, short8* bh, short8* bl) {
    const int sw = (li & emask) << 4;
    const char* rh = H + li * rowb;
    const char* rl = L + li * rowb;
#pragma unroll
    for (int kt = 0; kt < KT; ++kt) {
        const int off = (kt * 64 + q * 16) ^ sw;
        bh[kt] = *(const short8*)(rh + off);
        bl[kt] = *(const short8*)(rl + off);
    }
}

#define MFMA16(a, b, c) __builtin_amdgcn_mfma_f32_16x16x32_bf16(a, b, c, 0, 0, 0)

// ---------- register-resident-weight layer (edge kernel) ----------
// 3-term bf16x3: hi@hi + hi@lo + lo@hi (lo@lo ~2^-18 rel, dropped).
template<int KT, int MT, int WOFF>
__device__ __forceinline__ void layer_r(const short8 (&wh)[30], const short8 (&wl)[30],
                                        const float* __restrict__ bias, int q,
                                        const short8* bh, const short8* bl, f32x4* acc) {
#pragma unroll
    for (int mt = 0; mt < MT; ++mt) {
        const float4 bv = *(const float4*)(bias + mt * 16 + q * 4);
        acc[mt][0] = bv.x; acc[mt][1] = bv.y; acc[mt][2] = bv.z; acc[mt][3] = bv.w;
    }
#pragma unroll
    for (int kt = 0; kt < KT; ++kt) {
#pragma unroll
        for (int mt = 0; mt < MT; ++mt) acc[mt] = MFMA16(wh[WOFF + mt * KT + kt], bh[kt], acc[mt]);
#pragma unroll
        for (int mt = 0; mt < MT; ++mt) acc[mt] = MFMA16(wh[WOFF + mt * KT + kt], bl[kt], acc[mt]);
#pragma unroll
        for (int mt = 0; mt < MT; ++mt) acc[mt] = MFMA16(wl[WOFF + mt * KT + kt], bh[kt], acc[mt]);
    }
}

// ---------- pointer-based layer (node kernel, unchanged structure, 3-term) ----------
template<int KT, int MT, bool BIAS4>
__device__ __forceinline__ void do_layer(const char* __restrict__ wf, const float* __restrict__ bias,
                                         const short8* bh, const short8* bl,
                                         int lane, f32x4* acc, int nReal) {
    const int q = lane >> 4;
#pragma unroll
    for (int mt = 0; mt < MT; ++mt) {
        if constexpr (BIAS4) {
            const float4 bv = *(const float4*)(bias + mt * 16 + q * 4);
            acc[mt][0] = bv.x; acc[mt][1] = bv.y; acc[mt][2] = bv.z; acc[mt][3] = bv.w;
        } else {
#pragma unroll
            for (int r = 0; r < 4; ++r) {
                const int ch = mt * 16 + q * 4 + r;
                acc[mt][r] = (ch < nReal) ? bias[ch] : 0.0f;
            }
        }
    }
#pragma unroll
    for (int kt = 0; kt < KT; ++kt) {
        short8 wh[MT], wl[MT];
#pragma unroll
        for (int mt = 0; mt < MT; ++mt) {
            const char* p = wf + (size_t)(mt * KT + kt) * 2048 + lane * 16;
            wh[mt] = *(const short8*)p;
            wl[mt] = *(const short8*)(p + 1024);
        }
#pragma unroll
        for (int mt = 0; mt < MT; ++mt) acc[mt] = MFMA16(wh[mt], bh[kt], acc[mt]);
#pragma unroll
        for (int mt = 0; mt < MT; ++mt) acc[mt] = MFMA16(wh[mt], bl[kt], acc[mt]);
#pragma unroll
        for (int mt = 0; mt < MT; ++mt) acc[mt] = MFMA16(wl[mt], bh[kt], acc[mt]);
    }
}

// ReLU + hi/lo split + packed b32 writes into swizzled LDS.
template<int MT>
__device__ __forceinline__ void store_acts(char* H, char* L, int rowb, int emask,
                                           int lane, const f32x4* acc) {
    const int li = lane & 15, q = lane >> 4;
    const int sw = (li & emask) << 4;
    char* rh = H + li * rowb;
    char* rl = L + li * rowb;
#pragma unroll
    for (int mt = 0; mt < MT; ++mt) {
        const float v0 = fmaxf(acc[mt][0], 0.f), v1 = fmaxf(acc[mt][1], 0.f);
        const float v2 = fmaxf(acc[mt][2], 0.f), v3 = fmaxf(acc[mt][3], 0.f);
        uint h01, l01, h23, l23;
        split2(v0, v1, h01, l01);
        split2(v2, v3, h23, l23);
        const int off = (mt * 32 + q * 8) ^ sw;
        *(uint*)(rh + off) = h01; *(uint*)(rh + off + 4) = h23;
        *(uint*)(rl + off) = l01; *(uint*)(rl + off + 4) = l23;
    }
}

#define DECL_LDS \
    __shared__ __align__(16) char XH0[16 * 64];  __shared__ __align__(16) char XL0[16 * 64];  \
    __shared__ __align__(16) char XH1[16 * 256]; __shared__ __align__(16) char XL1[16 * 256]; \
    __shared__ __align__(16) char XH2[16 * 128]; __shared__ __align__(16) char XL2[16 * 128];

// ---------------- edge MLP: weights resident in VGPRs, grid-stride panels ----------------
template<int CSR>
__global__ __launch_bounds__(64, 1) void edge_mlp_r(
    const float* __restrict__ rel, const int* __restrict__ recv, const int* __restrict__ posOf,
    const char* __restrict__ wfrag,
    const float* __restrict__ b0, const float* __restrict__ b1, const float* __restrict__ b2,
    const float* __restrict__ b3, const float* __restrict__ b4,
    float* __restrict__ outp /* msg (CSR) or agg (atomic) */) {
    DECL_LDS
    const int lane = threadIdx.x;
    const int li = lane & 15, q = lane >> 4;
    const int se = lane >> 2, sc = lane & 3;   // staging coords

    // one-time: all 30 weight fragments (hi+lo) -> 240 VGPRs
    short8 wh[30], wl[30];
#pragma unroll
    for (int f = 0; f < 30; ++f) {
        const char* pp = wfrag + (size_t)f * 2048 + lane * 16;
        wh[f] = *(const short8*)pp;
        wl[f] = *(const short8*)(pp + 1024);
    }

    constexpr int NP = BB * (EE / 16);
    const int stride = gridDim.x;

    int p = blockIdx.x;
    if (p >= NP) return;
    float4 rv; int idx0;
    {
        const int b = p / (EE / 16), eg0 = (p % (EE / 16)) * 16;
        rv = *(const float4*)(rel + ((size_t)b * EE + eg0 + se) * 16 + sc * 4);
        idx0 = CSR ? posOf[eg0 + li] : recv[eg0 + li];
    }
    while (true) {
        const int b = p / (EE / 16);
        const int pn = p + stride;
        float4 rn = {0.f, 0.f, 0.f, 0.f}; int idxn = 0;
        if (pn < NP) {   // prefetch next panel's inputs during this panel's compute
            const int bn = pn / (EE / 16), egn = (pn % (EE / 16)) * 16;
            rn = *(const float4*)(rel + ((size_t)bn * EE + egn + se) * 16 + sc * 4);
            idxn = CSR ? posOf[egn + li] : recv[egn + li];
        }
        {   // stage rv -> X0 ([16 edges][32 ch], ch16..31 zero)
            uint h01, l01, h23, l23;
            split2(rv.x, rv.y, h01, l01);
            split2(rv.z, rv.w, h23, l23);
            const int sw = (se & 3) << 4;
            char* rh = XH0 + se * 64; char* rl = XL0 + se * 64;
            const int o = (sc * 8) ^ sw;
            *(uint*)(rh + o) = h01; *(uint*)(rh + o + 4) = h23;
            *(uint*)(rl + o) = l01; *(uint*)(rl + o + 4) = l23;
            const int oz = (32 + sc * 8) ^ sw;
            *(uint*)(rh + oz) = 0; *(uint*)(rh + oz + 4) = 0;
            *(uint*)(rl + oz) = 0; *(uint*)(rl + oz + 4) = 0;
        }
        short8 bh[4], bl[4];
        f32x4 a8[8], a4[4], a2[2], a1[1];

        loadB<1>(XH0, XL0, 64, 3, li, q, bh, bl);
        layer_r<1, 8, 0 >(wh, wl, b0, q, bh, bl, a8);
        store_acts<8>(XH1, XL1, 256, 7, lane, a8);

        loadB<4>(XH1, XL1, 256, 7, li, q, bh, bl);
        layer_r<4, 4, 8 >(wh, wl, b1, q, bh, bl, a4);
        store_acts<4>(XH2, XL2, 128, 7, lane, a4);

        loadB<2>(XH2, XL2, 128, 7, li, q, bh, bl);
        layer_r<2, 2, 24>(wh, wl, b2, q, bh, bl, a2);
        store_acts<2>(XH0, XL0, 64, 3, lane, a2);

        loadB<1>(XH0, XL0, 64, 3, li, q, bh, bl);
        layer_r<1, 1, 28>(wh, wl, b3, q, bh, bl, a1);
        store_acts<1>(XH2, XL2, 128, 7, lane, a1);
        {   // zero-pad ch16..31 of the K=32 container in X2
            const int sw = (li & 7) << 4;
            const int oz = (32 + q * 8) ^ sw;
            *(uint*)(XH2 + li * 128 + oz) = 0; *(uint*)(XH2 + li * 128 + oz + 4) = 0;
            *(uint*)(XL2 + li * 128 + oz) = 0; *(uint*)(XL2 + li * 128 + oz + 4) = 0;
        }
        loadB<1>(XH2, XL2, 128, 7, li, q, bh, bl);
        layer_r<1, 1, 29>(wh, wl, b4, q, bh, bl, a1);

        if (CSR) {
            float4 v;
            v.x = a1[0][0]; v.y = a1[0][1]; v.z = a1[0][2]; v.w = a1[0][3];
            *(float4*)(outp + ((size_t)b * EE + idx0) * 16 + q * 4) = v;
        } else {
            float* dst = outp + ((size_t)b * NN + idx0) * 16 + q * 4;
            atomicAdd(dst + 0, a1[0][0]); atomicAdd(dst + 1, a1[0][1]);
            atomicAdd(dst + 2, a1[0][2]); atomicAdd(dst + 3, a1[0][3]);
        }
        if (pn >= NP) break;
        p = pn; rv = rn; idx0 = idxn;
    }
}

// ---------------- node MLP: 16-node panel per wave ----------------
__global__ __launch_bounds__(64, 3) void node_mlp(
    const float* __restrict__ dyn, const float* __restrict__ agg,
    const char* __restrict__ wfrag,
    const float* __restrict__ b0, const float* __restrict__ b1, const float* __restrict__ b2,
    const float* __restrict__ b3, const float* __restrict__ b4,
    float* __restrict__ out) {
    DECL_LDS
    const int lane = threadIdx.x;
    const int li = lane & 15, q = lane >> 4;
    const int b = blockIdx.x / (NN / 16);
    const int ng0 = (blockIdx.x % (NN / 16)) * 16;

    {   // stage concat(dyn[14], agg[16]) -> X0 [16 nodes][32 ch], ch30..31 zero
        const int n = lane >> 2, p = lane & 3;
        const size_t dbase = ((size_t)b * NN + ng0 + n) * 14;
        const size_t abase = ((size_t)b * NN + ng0 + n) * 16;
        float qa0, qa1, qa2, qa3, qb0, qb1, qb2, qb3;
        if (p < 3) {
            const float2 u = *(const float2*)(dyn + dbase + 4 * p);
            const float2 w = *(const float2*)(dyn + dbase + 4 * p + 2);
            qa0 = u.x; qa1 = u.y; qa2 = w.x; qa3 = w.y;
            const float2 g0 = *(const float2*)(agg + abase + 2 + 4 * p);
            const float2 g1 = *(const float2*)(agg + abase + 4 + 4 * p);
            qb0 = g0.x; qb1 = g0.y; qb2 = g1.x; qb3 = g1.y;
        } else {
            const float2 u = *(const float2*)(dyn + dbase + 12);
            const float2 g = *(const float2*)(agg + abase + 0);
            qa0 = u.x; qa1 = u.y; qa2 = g.x; qa3 = g.y;
            const float2 g2 = *(const float2*)(agg + abase + 14);
            qb0 = g2.x; qb1 = g2.y; qb2 = 0.f; qb3 = 0.f;
        }
        const int sw = (n & 3) << 4;
        char* rh = XH0 + n * 64; char* rl = XL0 + n * 64;
        uint h01, l01, h23, l23;
        split2(qa0, qa1, h01, l01);
        split2(qa2, qa3, h23, l23);
        const int o = (p * 8) ^ sw;
        *(uint*)(rh + o) = h01; *(uint*)(rh + o + 4) = h23;
        *(uint*)(rl + o) = l01; *(uint*)(rl + o + 4) = l23;
        split2(qb0, qb1, h01, l01);
        split2(qb2, qb3, h23, l23);
        const int o2 = (32 + p * 8) ^ sw;
        *(uint*)(rh + o2) = h01; *(uint*)(rh + o2 + 4) = h23;
        *(uint*)(rl + o2) = l01; *(uint*)(rl + o2 + 4) = l23;
    }
    short8 bh[4], bl[4];
    f32x4 a8[8], a4[4], a2[2], a1[1];

    loadB<1>(XH0, XL0, 64, 3, li, q, bh, bl);
    do_layer<1, 8, true>(wfrag + 61440, b0, bh, bl, lane, a8, 128);
    store_acts<8>(XH1, XL1, 256, 7, lane, a8);

    loadB<4>(XH1, XL1, 256, 7, li, q, bh, bl);
    do_layer<4, 4, true>(wfrag + 77824, b1, bh, bl, lane, a4, 64);
    store_acts<4>(XH2, XL2, 128, 7, lane, a4);

    loadB<2>(XH2, XL2, 128, 7, li, q, bh, bl);
    do_layer<2, 2, true>(wfrag + 110592, b2, bh, bl, lane, a2, 32);
    store_acts<2>(XH0, XL0, 64, 3, lane, a2);

    loadB<1>(XH0, XL0, 64, 3, li, q, bh, bl);
    do_layer<1, 1, true>(wfrag + 118784, b3, bh, bl, lane, a1, 16);
    store_acts<1>(XH2, XL2, 128, 7, lane, a1);
    {
        const int sw = (li & 7) << 4;
        const int oz = (32 + q * 8) ^ sw;
        *(uint*)(XH2 + li * 128 + oz) = 0; *(uint*)(XH2 + li * 128 + oz + 4) = 0;
        *(uint*)(XL2 + li * 128 + oz) = 0; *(uint*)(XL2 + li * 128 + oz + 4) = 0;
    }
    loadB<1>(XH2, XL2, 128, 7, li, q, bh, bl);
    do_layer<1, 1, false>(wfrag + 120832, b4, bh, bl, lane, a1, 6);

    const int gn = ng0 + li;
#pragma unroll
    for (int r = 0; r < 4; ++r) {
        const int ch = q * 4 + r;
        if (ch < 6) out[((size_t)b * NN + gn) * 6 + ch] = a1[0][r];
    }
}

// ---------------- weight prep: pack hi/lo bf16 A-fragments ----------------
__global__ __launch_bounds__(64) void wprep(
    const float* w0f, const float* w1f, const float* w2f, const float* w3f, const float* w4f,
    const float* w0d, const float* w1d, const float* w2d, const float* w3d, const float* w4d,
    char* __restrict__ wfrag) {
    const int bid = blockIdx.x;  // 0..59
    const int lane = threadIdx.x;
    const int net = bid / 30;
    const int r = bid % 30;
    int l, base;
    if (r < 8)       { l = 0; base = 0; }
    else if (r < 24) { l = 1; base = 8; }
    else if (r < 28) { l = 2; base = 24; }
    else if (r < 29) { l = 3; base = 28; }
    else             { l = 4; base = 29; }
    const int KTs[5] = {1, 4, 2, 1, 1};
    const int Krf[5] = {16, 128, 64, 32, 16};
    const int Krd[5] = {30, 128, 64, 32, 16};
    const int Ncf[5] = {128, 64, 32, 16, 16};
    const int Ncd[5] = {128, 64, 32, 16, 6};
    const float* Wf[5] = {w0f, w1f, w2f, w3f, w4f};
    const float* Wd[5] = {w0d, w1d, w2d, w3d, w4d};
    const int KT = KTs[l];
    const int idx = r - base;
    const int mt = idx / KT, kt = idx % KT;
    const int Kreal = net ? Krd[l] : Krf[l];
    const int Ncol  = net ? Ncd[l] : Ncf[l];
    const float* W  = net ? Wd[l] : Wf[l];
    const int ch = mt * 16 + (lane & 15);
    uint hi[4], lo[4];
#pragma unroll
    for (int t = 0; t < 4; ++t) {
        float x = 0.f, y = 0.f;
        const int k0 = kt * 32 + (lane >> 4) * 8 + 2 * t;
        if (k0 < Kreal && ch < Ncol) x = W[(size_t)k0 * Ncol + ch];
        if (k0 + 1 < Kreal && ch < Ncol) y = W[(size_t)(k0 + 1) * Ncol + ch];
        split2(x, y, hi[t], lo[t]);
    }
    uint4 H; H.x = hi[0]; H.y = hi[1]; H.z = hi[2]; H.w = hi[3];
    uint4 L; L.x = lo[0]; L.y = lo[1]; L.z = lo[2]; L.w = lo[3];
    *(uint4*)(wfrag + (size_t)bid * 2048 + lane * 16) = H;
    *(uint4*)(wfrag + (size_t)bid * 2048 + 1024 + lane * 16) = L;
}

// ---------------- CSR build + gather ----------------
__global__ void count_k(const int* __restrict__ recv, int* __restrict__ counts) {
    const int e = blockIdx.x * 256 + threadIdx.x;
    if (e < EE) atomicAdd(&counts[recv[e]], 1);
}

__global__ __launch_bounds__(1024) void scan_k(const int* __restrict__ counts,
                                               int* __restrict__ start, int* __restrict__ cursor) {
    __shared__ int part[1024];
    const int t = threadIdx.x;
    const int lo = t * 20, hi = lo + 20 < NN ? lo + 20 : NN;
    int s = 0;
    for (int i = lo; i < hi; ++i) s += counts[i];
    part[t] = s;
    __syncthreads();
    for (int d = 1; d < 1024; d <<= 1) {
        int v = 0;
        if (t >= d) v = part[t - d];
        __syncthreads();
        part[t] += v;
        __syncthreads();
    }
    int run = t ? part[t - 1] : 0;
    for (int i = lo; i < hi; ++i) { start[i] = run; cursor[i] = run; run += counts[i]; }
    if (t == 0) start[NN] = EE;
}

__global__ void fill_k(const int* __restrict__ recv, int* __restrict__ cursor,
                       int* __restrict__ posOf) {
    const int e = blockIdx.x * 256 + threadIdx.x;
    if (e < EE) posOf[e] = atomicAdd(&cursor[recv[e]], 1);
}

__global__ void gather_k(const float* __restrict__ msg, const int* __restrict__ start,
                         float* __restrict__ agg) {
    const int t = blockIdx.x * 256 + threadIdx.x;  // (b*NN+n)*4 + oq
    if (t >= BB * NN * 4) return;
    const int oq = t & 3;
    const int bn = t >> 2;
    const int n = bn % NN, b = bn / NN;
    const int s = start[n], e = start[n + 1];
    float4 S; S.x = 0.f; S.y = 0.f; S.z = 0.f; S.w = 0.f;
    for (int i = s; i < e; ++i) {
        const float4 v = *(const float4*)(msg + ((size_t)b * EE + i) * 16 + oq * 4);
        S.x += v.x; S.y += v.y; S.z += v.z; S.w += v.w;
    }
    *(float4*)(agg + (size_t)bn * 16 + oq * 4) = S;
}

extern "C" void kernel_launch(void* const* d_in, const int* in_sizes, int n_in,
                              void* d_out, int out_size, void* d_ws, size_t ws_size,
                              hipStream_t stream) {
    const float* dyn = (const float*)d_in[0];
    const float* rel = (const float*)d_in[1];
    const int* recv = (const int*)d_in[3];  // send (d_in[2]) unused by reference

    const float* fw[5]; const float* fb[5]; const float* dw[5]; const float* db[5];
    for (int i = 0; i < 5; ++i) {
        fw[i] = (const float*)d_in[4 + 2 * i];
        fb[i] = (const float*)d_in[5 + 2 * i];
        dw[i] = (const float*)d_in[14 + 2 * i];
        db[i] = (const float*)d_in[15 + 2 * i];
    }

    char* ws = (char*)d_ws;
    char* wfrag = ws;  // 122880 B used, padded to 131072
    const size_t MSG_OFF = 131072;
    const size_t MSG_SZ = (size_t)BB * EE * 16 * 4;          // 81,920,000
    const size_t POS_OFF = MSG_OFF + MSG_SZ;                 // 82,051,072
    const size_t CNT_OFF = POS_OFF + (size_t)EE * 4;         // 84,611,072
    const size_t CUR_OFF = CNT_OFF + (size_t)NN * 4;         // 84,691,072
    const size_t STA_OFF = CUR_OFF + (size_t)NN * 4;         // 84,771,072
    const size_t AGG_OFF_CSR = STA_OFF + 80128;              // 84,851,200 (16B aligned)
    const size_t NEED = AGG_OFF_CSR + (size_t)BB * NN * 16 * 4;  // 87,411,200
    const bool csr = ws_size >= NEED;

    wprep<<<60, 64, 0, stream>>>(fw[0], fw[1], fw[2], fw[3], fw[4],
                                 dw[0], dw[1], dw[2], dw[3], dw[4], wfrag);

    float* agg;
    if (csr) {
        float* msg = (float*)(ws + MSG_OFF);
        int* posOf = (int*)(ws + POS_OFF);
        int* counts = (int*)(ws + CNT_OFF);
        int* cursor = (int*)(ws + CUR_OFF);
        int* start = (int*)(ws + STA_OFF);
        agg = (float*)(ws + AGG_OFF_CSR);

        hipMemsetAsync(counts, 0, (size_t)NN * 4, stream);
        count_k<<<(EE + 255) / 256, 256, 0, stream>>>(recv, counts);
        scan_k<<<1, 1024, 0, stream>>>(counts, start, cursor);
        fill_k<<<(EE + 255) / 256, 256, 0, stream>>>(recv, cursor, posOf);
        edge_mlp_r<1><<<4096, 64, 0, stream>>>(
            rel, recv, posOf, wfrag, fb[0], fb[1], fb[2], fb[3], fb[4], msg);
        gather_k<<<(BB * NN * 4 + 255) / 256, 256, 0, stream>>>(msg, start, agg);
    } else {
        agg = (float*)(ws + MSG_OFF);
        hipMemsetAsync(agg, 0, (size_t)BB * NN * 16 * 4, stream);
        edge_mlp_r<0><<<4096, 64, 0, stream>>>(
            rel, recv, nullptr, wfrag, fb[0], fb[1], fb[2], fb[3], fb[4], agg);
    }

    node_mlp<<<BB * (NN / 16), 64, 0, stream>>>(
        dyn, agg, wfrag, db[0], db[1], db[2], db[3], db[4], (float*)d_out);
}

// Round 9
// 471.232 us; speedup vs baseline: 3.1737x; 1.1102x over previous
//
#include <hip/hip_runtime.h>
#include <hip/hip_bf16.h>

#define BB 2
#define NN 20000
#define EE 640000

using short8 = __attribute__((ext_vector_type(8))) short;
using f32x4  = __attribute__((ext_vector_type(4))) float;
typedef unsigned int uint;

// ---------- bf16 split helpers: native RNE cvt (compiler emits cvt_pk) ----------
__device__ __forceinline__ uint b16u(float x) {
    return (uint)__bfloat16_as_ushort(__float2bfloat16(x));
}
__device__ __forceinline__ void split2(float x, float y, uint& hi, uint& lo) {
    const uint hx = b16u(x), hy = b16u(y);
    hi = hx | (hy << 16);
    const float fx = __uint_as_float(hx << 16), fy = __uint_as_float(hy << 16);
    lo = b16u(x - fx) | (b16u(y - fy) << 16);
}

// ---------- B-fragment load from swizzled LDS ----------
template<int KT>
__device__ __forceinline__ void loadB(const char* H, const char* L, int rowb, int emask,
                                      int li, int q, short8* bh, short8* bl) {
    const int sw = (li & emask) << 4;
    const char* rh = H + li * rowb;
    const char* rl = L + li * rowb;
#pragma unroll
    for (int kt = 0; kt < KT; ++kt) {
        const int off = (kt * 64 + q * 16) ^ sw;
        bh[kt] = *(const short8*)(rh + off);
        bl[kt] = *(const short8*)(rl + off);
    }
}

#define MFMA16(a, b, c) __builtin_amdgcn_mfma_f32_16x16x32_bf16(a, b, c, 0, 0, 0)

// ---------- register-resident-weight layer, bias from LDS ----------
// 3-term bf16x3: hi@hi + hi@lo + lo@hi (lo@lo ~2^-18 rel, dropped).
template<int KT, int MT, int WOFF>
__device__ __forceinline__ void layer_r(const short8 (&wh)[30], const short8 (&wl)[30],
                                        const float* bias, int q,
                                        const short8* bh, const short8* bl, f32x4* acc) {
#pragma unroll
    for (int mt = 0; mt < MT; ++mt) {
        const float4 bv = *(const float4*)(bias + mt * 16 + q * 4);
        acc[mt][0] = bv.x; acc[mt][1] = bv.y; acc[mt][2] = bv.z; acc[mt][3] = bv.w;
    }
#pragma unroll
    for (int kt = 0; kt < KT; ++kt) {
#pragma unroll
        for (int mt = 0; mt < MT; ++mt) acc[mt] = MFMA16(wh[WOFF + mt * KT + kt], bh[kt], acc[mt]);
#pragma unroll
        for (int mt = 0; mt < MT; ++mt) acc[mt] = MFMA16(wh[WOFF + mt * KT + kt], bl[kt], acc[mt]);
#pragma unroll
        for (int mt = 0; mt < MT; ++mt) acc[mt] = MFMA16(wl[WOFF + mt * KT + kt], bh[kt], acc[mt]);
    }
}

// ReLU + hi/lo split + packed b32 writes into swizzled LDS.
template<int MT>
__device__ __forceinline__ void store_acts(char* H, char* L, int rowb, int emask,
                                           int lane, const f32x4* acc) {
    const int li = lane & 15, q = lane >> 4;
    const int sw = (li & emask) << 4;
    char* rh = H + li * rowb;
    char* rl = L + li * rowb;
#pragma unroll
    for (int mt = 0; mt < MT; ++mt) {
        const float v0 = fmaxf(acc[mt][0], 0.f), v1 = fmaxf(acc[mt][1], 0.f);
        const float v2 = fmaxf(acc[mt][2], 0.f), v3 = fmaxf(acc[mt][3], 0.f);
        uint h01, l01, h23, l23;
        split2(v0, v1, h01, l01);
        split2(v2, v3, h23, l23);
        const int off = (mt * 32 + q * 8) ^ sw;
        *(uint*)(rh + off) = h01; *(uint*)(rh + off + 4) = h23;
        *(uint*)(rl + off) = l01; *(uint*)(rl + off + 4) = l23;
    }
}

// stage 16 input channels (float4 per lane, 4 lanes/row) into padded X0 [16][128B], emask 7
__device__ __forceinline__ void stage16(char* H, char* L, int se, int sc, float4 v) {
    uint h01, l01, h23, l23;
    split2(v.x, v.y, h01, l01);
    split2(v.z, v.w, h23, l23);
    const int sw = (se & 7) << 4;
    char* rh = H + se * 128; char* rl = L + se * 128;
    const int o = (sc * 8) ^ sw;
    *(uint*)(rh + o) = h01; *(uint*)(rh + o + 4) = h23;
    *(uint*)(rl + o) = l01; *(uint*)(rl + o + 4) = l23;
    const int oz = (32 + sc * 8) ^ sw;
    *(uint*)(rh + oz) = 0; *(uint*)(rh + oz + 4) = 0;
    *(uint*)(rl + oz) = 0; *(uint*)(rl + oz + 4) = 0;
}

// zero-pad ch16..31 of the K=32 container in an X2-shaped buffer
__device__ __forceinline__ void padX2(char* H, char* L, int li, int q) {
    const int sw = (li & 7) << 4;
    const int oz = (32 + q * 8) ^ sw;
    *(uint*)(H + li * 128 + oz) = 0; *(uint*)(H + li * 128 + oz + 4) = 0;
    *(uint*)(L + li * 128 + oz) = 0; *(uint*)(L + li * 128 + oz + 4) = 0;
}

// ---------------- edge MLP: weights in regs, TWO panels in flight per wave ----------------
template<int CSR>
__global__ __launch_bounds__(64, 1) void edge_mlp2(
    const float* __restrict__ rel, const int* __restrict__ recv, const int* __restrict__ posOf,
    const char* __restrict__ wfrag,
    const float* __restrict__ b0, const float* __restrict__ b1, const float* __restrict__ b2,
    const float* __restrict__ b3, const float* __restrict__ b4,
    float* __restrict__ outp) {
    __shared__ __align__(16) char XA0H[16 * 128], XA0L[16 * 128];
    __shared__ __align__(16) char XA1H[16 * 256], XA1L[16 * 256];
    __shared__ __align__(16) char XA2H[16 * 128], XA2L[16 * 128];
    __shared__ __align__(16) char XB0H[16 * 128], XB0L[16 * 128];
    __shared__ __align__(16) char XB1H[16 * 256], XB1L[16 * 256];
    __shared__ __align__(16) char XB2H[16 * 128], XB2L[16 * 128];
    __shared__ __align__(16) float BIAS[256];

    const int lane = threadIdx.x;
    const int li = lane & 15, q = lane >> 4;
    const int se = lane >> 2, sc = lane & 3;

    // stage biases -> LDS (layout: b0@0, b1@128, b2@192, b3@224, b4@240)
    if (lane < 32)      *(float4*)&BIAS[lane * 4] = *(const float4*)(b0 + lane * 4);
    else if (lane < 48) *(float4*)&BIAS[128 + (lane - 32) * 4] = *(const float4*)(b1 + (lane - 32) * 4);
    else if (lane < 56) *(float4*)&BIAS[192 + (lane - 48) * 4] = *(const float4*)(b2 + (lane - 48) * 4);
    else if (lane < 60) *(float4*)&BIAS[224 + (lane - 56) * 4] = *(const float4*)(b3 + (lane - 56) * 4);
    else                *(float4*)&BIAS[240 + (lane - 60) * 4] = *(const float4*)(b4 + (lane - 60) * 4);

    // all 30 weight fragments (hi+lo), 240 regs
    short8 wh[30], wl[30];
#pragma unroll
    for (int f = 0; f < 30; ++f) {
        const char* pp = wfrag + (size_t)f * 2048 + lane * 16;
        wh[f] = *(const short8*)pp;
        wl[f] = *(const short8*)(pp + 1024);
    }

    constexpr int PPB = EE / 16;         // panels per batch = 40000
    constexpr int NPAIR = BB * PPB / 2;  // 40000 pairs
    const int G = gridDim.x;

    int pr = blockIdx.x;
    if (pr >= NPAIR) return;

    float4 rvA, rvB; int ixA, ixB;
    {
        const int pA = 2 * pr;
        const int bb = pA / PPB, e0 = (pA % PPB) * 16;
        rvA = *(const float4*)(rel + ((size_t)bb * EE + e0 + se) * 16 + sc * 4);
        rvB = *(const float4*)(rel + ((size_t)bb * EE + e0 + 16 + se) * 16 + sc * 4);
        ixA = CSR ? posOf[e0 + li] : recv[e0 + li];
        ixB = CSR ? posOf[e0 + 16 + li] : recv[e0 + 16 + li];
    }

    while (true) {
        const int pA = 2 * pr;
        const int bA = pA / PPB;
        const int prn = pr + G;
        const bool more = prn < NPAIR;
        float4 rnA = {0.f, 0.f, 0.f, 0.f}, rnB = {0.f, 0.f, 0.f, 0.f};
        int jxA = 0, jxB = 0;
        if (more) {  // prefetch next pair during this pair's compute
            const int pN = 2 * prn;
            const int bb = pN / PPB, e0 = (pN % PPB) * 16;
            rnA = *(const float4*)(rel + ((size_t)bb * EE + e0 + se) * 16 + sc * 4);
            rnB = *(const float4*)(rel + ((size_t)bb * EE + e0 + 16 + se) * 16 + sc * 4);
            jxA = CSR ? posOf[e0 + li] : recv[e0 + li];
            jxB = CSR ? posOf[e0 + 16 + li] : recv[e0 + 16 + li];
        }

        stage16(XA0H, XA0L, se, sc, rvA);
        stage16(XB0H, XB0L, se, sc, rvB);

        short8 bhA[4], blA[4], bhB[4], blB[4];
        f32x4 aA[8], aB[8];

        // L1: 16->128
        loadB<1>(XA0H, XA0L, 128, 7, li, q, bhA, blA);
        loadB<1>(XB0H, XB0L, 128, 7, li, q, bhB, blB);
        layer_r<1, 8, 0>(wh, wl, BIAS + 0, q, bhA, blA, aA);
        store_acts<8>(XA1H, XA1L, 256, 7, lane, aA);
        layer_r<1, 8, 0>(wh, wl, BIAS + 0, q, bhB, blB, aB);
        store_acts<8>(XB1H, XB1L, 256, 7, lane, aB);
        // L2: 128->64
        loadB<4>(XA1H, XA1L, 256, 7, li, q, bhA, blA);
        loadB<4>(XB1H, XB1L, 256, 7, li, q, bhB, blB);
        layer_r<4, 4, 8>(wh, wl, BIAS + 128, q, bhA, blA, aA);
        store_acts<4>(XA2H, XA2L, 128, 7, lane, aA);
        layer_r<4, 4, 8>(wh, wl, BIAS + 128, q, bhB, blB, aB);
        store_acts<4>(XB2H, XB2L, 128, 7, lane, aB);
        // L3: 64->32
        loadB<2>(XA2H, XA2L, 128, 7, li, q, bhA, blA);
        loadB<2>(XB2H, XB2L, 128, 7, li, q, bhB, blB);
        layer_r<2, 2, 24>(wh, wl, BIAS + 192, q, bhA, blA, aA);
        store_acts<2>(XA0H, XA0L, 128, 7, lane, aA);
        layer_r<2, 2, 24>(wh, wl, BIAS + 192, q, bhB, blB, aB);
        store_acts<2>(XB0H, XB0L, 128, 7, lane, aB);
        // L4: 32->16
        loadB<1>(XA0H, XA0L, 128, 7, li, q, bhA, blA);
        loadB<1>(XB0H, XB0L, 128, 7, li, q, bhB, blB);
        layer_r<1, 1, 28>(wh, wl, BIAS + 224, q, bhA, blA, aA);
        store_acts<1>(XA2H, XA2L, 128, 7, lane, aA);
        layer_r<1, 1, 28>(wh, wl, BIAS + 224, q, bhB, blB, aB);
        store_acts<1>(XB2H, XB2L, 128, 7, lane, aB);
        padX2(XA2H, XA2L, li, q);
        padX2(XB2H, XB2L, li, q);
        // L5: 16->16
        loadB<1>(XA2H, XA2L, 128, 7, li, q, bhA, blA);
        loadB<1>(XB2H, XB2L, 128, 7, li, q, bhB, blB);
        layer_r<1, 1, 29>(wh, wl, BIAS + 240, q, bhA, blA, aA);
        layer_r<1, 1, 29>(wh, wl, BIAS + 240, q, bhB, blB, aB);

        if (CSR) {
            float4 vA, vB;
            vA.x = aA[0][0]; vA.y = aA[0][1]; vA.z = aA[0][2]; vA.w = aA[0][3];
            vB.x = aB[0][0]; vB.y = aB[0][1]; vB.z = aB[0][2]; vB.w = aB[0][3];
            *(float4*)(outp + ((size_t)bA * EE + ixA) * 16 + q * 4) = vA;
            *(float4*)(outp + ((size_t)bA * EE + ixB) * 16 + q * 4) = vB;
        } else {
            float* dA = outp + ((size_t)bA * NN + ixA) * 16 + q * 4;
            atomicAdd(dA + 0, aA[0][0]); atomicAdd(dA + 1, aA[0][1]);
            atomicAdd(dA + 2, aA[0][2]); atomicAdd(dA + 3, aA[0][3]);
            float* dB = outp + ((size_t)bA * NN + ixB) * 16 + q * 4;
            atomicAdd(dB + 0, aB[0][0]); atomicAdd(dB + 1, aB[0][1]);
            atomicAdd(dB + 2, aB[0][2]); atomicAdd(dB + 3, aB[0][3]);
        }
        if (!more) break;
        pr = prn; rvA = rnA; rvB = rnB; ixA = jxA; ixB = jxB;
    }
}

// ---------------- node MLP: register-resident weights, grid-stride ----------------
__global__ __launch_bounds__(64, 1) void node_mlp_r(
    const float* __restrict__ dyn, const float* __restrict__ agg,
    const char* __restrict__ wfrag,
    const float* __restrict__ b0, const float* __restrict__ b1, const float* __restrict__ b2,
    const float* __restrict__ b3, const float* __restrict__ b4,
    float* __restrict__ out) {
    __shared__ __align__(16) char XH0[16 * 128], XL0[16 * 128];
    __shared__ __align__(16) char XH1[16 * 256], XL1[16 * 256];
    __shared__ __align__(16) char XH2[16 * 128], XL2[16 * 128];
    __shared__ __align__(16) float BIAS[256];

    const int lane = threadIdx.x;
    const int li = lane & 15, q = lane >> 4;

    if (lane < 32)      *(float4*)&BIAS[lane * 4] = *(const float4*)(b0 + lane * 4);
    else if (lane < 48) *(float4*)&BIAS[128 + (lane - 32) * 4] = *(const float4*)(b1 + (lane - 32) * 4);
    else if (lane < 56) *(float4*)&BIAS[192 + (lane - 48) * 4] = *(const float4*)(b2 + (lane - 48) * 4);
    else if (lane < 60) *(float4*)&BIAS[224 + (lane - 56) * 4] = *(const float4*)(b3 + (lane - 56) * 4);
    else if (lane == 60) *(float4*)&BIAS[240] = *(const float4*)(b4);
    else if (lane == 61) { BIAS[244] = b4[4]; BIAS[245] = b4[5]; BIAS[246] = 0.f; BIAS[247] = 0.f; }
    else { BIAS[248 + (lane - 62) * 4] = 0.f; BIAS[249 + (lane - 62) * 4] = 0.f;
           BIAS[250 + (lane - 62) * 4] = 0.f; BIAS[251 + (lane - 62) * 4] = 0.f; }

    short8 wh[30], wl[30];
#pragma unroll
    for (int f = 0; f < 30; ++f) {
        const char* pp = wfrag + 61440 + (size_t)f * 2048 + lane * 16;
        wh[f] = *(const short8*)pp;
        wl[f] = *(const short8*)(pp + 1024);
    }

    constexpr int NPN = BB * (NN / 16);  // 2500
    for (int p = blockIdx.x; p < NPN; p += gridDim.x) {
        const int b = p / (NN / 16);
        const int ng0 = (p % (NN / 16)) * 16;
        {   // stage concat(dyn[14], agg[16]) -> X0 [16 nodes][32 ch container]
            const int n = lane >> 2, p4 = lane & 3;
            const size_t dbase = ((size_t)b * NN + ng0 + n) * 14;
            const size_t abase = ((size_t)b * NN + ng0 + n) * 16;
            float qa0, qa1, qa2, qa3, qb0, qb1, qb2, qb3;
            if (p4 < 3) {
                const float2 u = *(const float2*)(dyn + dbase + 4 * p4);
                const float2 w = *(const float2*)(dyn + dbase + 4 * p4 + 2);
                qa0 = u.x; qa1 = u.y; qa2 = w.x; qa3 = w.y;
                const float2 g0 = *(const float2*)(agg + abase + 2 + 4 * p4);
                const float2 g1 = *(const float2*)(agg + abase + 4 + 4 * p4);
                qb0 = g0.x; qb1 = g0.y; qb2 = g1.x; qb3 = g1.y;
            } else {
                const float2 u = *(const float2*)(dyn + dbase + 12);
                const float2 g = *(const float2*)(agg + abase + 0);
                qa0 = u.x; qa1 = u.y; qa2 = g.x; qa3 = g.y;
                const float2 g2 = *(const float2*)(agg + abase + 14);
                qb0 = g2.x; qb1 = g2.y; qb2 = 0.f; qb3 = 0.f;
            }
            const int sw = (n & 7) << 4;
            char* rh = XH0 + n * 128; char* rl = XL0 + n * 128;
            uint h01, l01, h23, l23;
            split2(qa0, qa1, h01, l01);
            split2(qa2, qa3, h23, l23);
            const int o = (p4 * 8) ^ sw;
            *(uint*)(rh + o) = h01; *(uint*)(rh + o + 4) = h23;
            *(uint*)(rl + o) = l01; *(uint*)(rl + o + 4) = l23;
            split2(qb0, qb1, h01, l01);
            split2(qb2, qb3, h23, l23);
            const int o2 = (32 + p4 * 8) ^ sw;
            *(uint*)(rh + o2) = h01; *(uint*)(rh + o2 + 4) = h23;
            *(uint*)(rl + o2) = l01; *(uint*)(rl + o2 + 4) = l23;
        }
        short8 bh[4], bl[4];
        f32x4 acc[8];

        loadB<1>(XH0, XL0, 128, 7, li, q, bh, bl);
        layer_r<1, 8, 0>(wh, wl, BIAS + 0, q, bh, bl, acc);
        store_acts<8>(XH1, XL1, 256, 7, lane, acc);

        loadB<4>(XH1, XL1, 256, 7, li, q, bh, bl);
        layer_r<4, 4, 8>(wh, wl, BIAS + 128, q, bh, bl, acc);
        store_acts<4>(XH2, XL2, 128, 7, lane, acc);

        loadB<2>(XH2, XL2, 128, 7, li, q, bh, bl);
        layer_r<2, 2, 24>(wh, wl, BIAS + 192, q, bh, bl, acc);
        store_acts<2>(XH0, XL0, 128, 7, lane, acc);

        loadB<1>(XH0, XL0, 128, 7, li, q, bh, bl);
        layer_r<1, 1, 28>(wh, wl, BIAS + 224, q, bh, bl, acc);
        store_acts<1>(XH2, XL2, 128, 7, lane, acc);
        padX2(XH2, XL2, li, q);

        loadB<1>(XH2, XL2, 128, 7, li, q, bh, bl);
        layer_r<1, 1, 29>(wh, wl, BIAS + 240, q, bh, bl, acc);

        const int gn = ng0 + li;
#pragma unroll
        for (int r = 0; r < 4; ++r) {
            const int ch = q * 4 + r;
            if (ch < 6) out[((size_t)b * NN + gn) * 6 + ch] = acc[0][r];
        }
    }
}

// ---------------- weight prep: pack hi/lo bf16 A-fragments ----------------
__global__ __launch_bounds__(64) void wprep(
    const float* w0f, const float* w1f, const float* w2f, const float* w3f, const float* w4f,
    const float* w0d, const float* w1d, const float* w2d, const float* w3d, const float* w4d,
    char* __restrict__ wfrag) {
    const int bid = blockIdx.x;  // 0..59
    const int lane = threadIdx.x;
    const int net = bid / 30;
    const int r = bid % 30;
    int l, base;
    if (r < 8)       { l = 0; base = 0; }
    else if (r < 24) { l = 1; base = 8; }
    else if (r < 28) { l = 2; base = 24; }
    else if (r < 29) { l = 3; base = 28; }
    else             { l = 4; base = 29; }
    const int KTs[5] = {1, 4, 2, 1, 1};
    const int Krf[5] = {16, 128, 64, 32, 16};
    const int Krd[5] = {30, 128, 64, 32, 16};
    const int Ncf[5] = {128, 64, 32, 16, 16};
    const int Ncd[5] = {128, 64, 32, 16, 6};
    const float* Wf[5] = {w0f, w1f, w2f, w3f, w4f};
    const float* Wd[5] = {w0d, w1d, w2d, w3d, w4d};
    const int KT = KTs[l];
    const int idx = r - base;
    const int mt = idx / KT, kt = idx % KT;
    const int Kreal = net ? Krd[l] : Krf[l];
    const int Ncol  = net ? Ncd[l] : Ncf[l];
    const float* W  = net ? Wd[l] : Wf[l];
    const int ch = mt * 16 + (lane & 15);
    uint hi[4], lo[4];
#pragma unroll
    for (int t = 0; t < 4; ++t) {
        float x = 0.f, y = 0.f;
        const int k0 = kt * 32 + (lane >> 4) * 8 + 2 * t;
        if (k0 < Kreal && ch < Ncol) x = W[(size_t)k0 * Ncol + ch];
        if (k0 + 1 < Kreal && ch < Ncol) y = W[(size_t)(k0 + 1) * Ncol + ch];
        split2(x, y, hi[t], lo[t]);
    }
    uint4 H; H.x = hi[0]; H.y = hi[1]; H.z = hi[2]; H.w = hi[3];
    uint4 L; L.x = lo[0]; L.y = lo[1]; L.z = lo[2]; L.w = lo[3];
    *(uint4*)(wfrag + (size_t)bid * 2048 + lane * 16) = H;
    *(uint4*)(wfrag + (size_t)bid * 2048 + 1024 + lane * 16) = L;
}

// ---------------- CSR build + gather ----------------
__global__ void count_k(const int* __restrict__ recv, int* __restrict__ counts) {
    const int e = blockIdx.x * 256 + threadIdx.x;
    if (e < EE) atomicAdd(&counts[recv[e]], 1);
}

__global__ __launch_bounds__(1024) void scan_k(const int* __restrict__ counts,
                                               int* __restrict__ start, int* __restrict__ cursor) {
    __shared__ int part[1024];
    const int t = threadIdx.x;
    const int lo = t * 20, hi = lo + 20 < NN ? lo + 20 : NN;
    int s = 0;
    for (int i = lo; i < hi; ++i) s += counts[i];
    part[t] = s;
    __syncthreads();
    for (int d = 1; d < 1024; d <<= 1) {
        int v = 0;
        if (t >= d) v = part[t - d];
        __syncthreads();
        part[t] += v;
        __syncthreads();
    }
    int run = t ? part[t - 1] : 0;
    for (int i = lo; i < hi; ++i) { start[i] = run; cursor[i] = run; run += counts[i]; }
    if (t == 0) start[NN] = EE;
}

__global__ void fill_k(const int* __restrict__ recv, int* __restrict__ cursor,
                       int* __restrict__ posOf) {
    const int e = blockIdx.x * 256 + threadIdx.x;
    if (e < EE) posOf[e] = atomicAdd(&cursor[recv[e]], 1);
}

__global__ void gather_k(const float* __restrict__ msg, const int* __restrict__ start,
                         float* __restrict__ agg) {
    const int t = blockIdx.x * 256 + threadIdx.x;  // (b*NN+n)*4 + oq
    if (t >= BB * NN * 4) return;
    const int oq = t & 3;
    const int bn = t >> 2;
    const int n = bn % NN, b = bn / NN;
    const int s = start[n], e = start[n + 1];
    float4 S; S.x = 0.f; S.y = 0.f; S.z = 0.f; S.w = 0.f;
    for (int i = s; i < e; ++i) {
        const float4 v = *(const float4*)(msg + ((size_t)b * EE + i) * 16 + oq * 4);
        S.x += v.x; S.y += v.y; S.z += v.z; S.w += v.w;
    }
    *(float4*)(agg + (size_t)bn * 16 + oq * 4) = S;
}

extern "C" void kernel_launch(void* const* d_in, const int* in_sizes, int n_in,
                              void* d_out, int out_size, void* d_ws, size_t ws_size,
                              hipStream_t stream) {
    const float* dyn = (const float*)d_in[0];
    const float* rel = (const float*)d_in[1];
    const int* recv = (const int*)d_in[3];  // send (d_in[2]) unused by reference

    const float* fw[5]; const float* fb[5]; const float* dw[5]; const float* db[5];
    for (int i = 0; i < 5; ++i) {
        fw[i] = (const float*)d_in[4 + 2 * i];
        fb[i] = (const float*)d_in[5 + 2 * i];
        dw[i] = (const float*)d_in[14 + 2 * i];
        db[i] = (const float*)d_in[15 + 2 * i];
    }

    char* ws = (char*)d_ws;
    char* wfrag = ws;  // 122880 B used, padded to 131072
    const size_t MSG_OFF = 131072;
    const size_t MSG_SZ = (size_t)BB * EE * 16 * 4;          // 81,920,000
    const size_t POS_OFF = MSG_OFF + MSG_SZ;                 // 82,051,072
    const size_t CNT_OFF = POS_OFF + (size_t)EE * 4;         // 84,611,072
    const size_t CUR_OFF = CNT_OFF + (size_t)NN * 4;         // 84,691,072
    const size_t STA_OFF = CUR_OFF + (size_t)NN * 4;         // 84,771,072
    const size_t AGG_OFF_CSR = STA_OFF + 80128;              // 84,851,200 (16B aligned)
    const size_t NEED = AGG_OFF_CSR + (size_t)BB * NN * 16 * 4;  // 87,411,200
    const bool csr = ws_size >= NEED;

    wprep<<<60, 64, 0, stream>>>(fw[0], fw[1], fw[2], fw[3], fw[4],
                                 dw[0], dw[1], dw[2], dw[3], dw[4], wfrag);

    float* agg;
    if (csr) {
        float* msg = (float*)(ws + MSG_OFF);
        int* posOf = (int*)(ws + POS_OFF);
        int* counts = (int*)(ws + CNT_OFF);
        int* cursor = (int*)(ws + CUR_OFF);
        int* start = (int*)(ws + STA_OFF);
        agg = (float*)(ws + AGG_OFF_CSR);

        hipMemsetAsync(counts, 0, (size_t)NN * 4, stream);
        count_k<<<(EE + 255) / 256, 256, 0, stream>>>(recv, counts);
        scan_k<<<1, 1024, 0, stream>>>(counts, start, cursor);
        fill_k<<<(EE + 255) / 256, 256, 0, stream>>>(recv, cursor, posOf);
        edge_mlp2<1><<<2048, 64, 0, stream>>>(
            rel, recv, posOf, wfrag, fb[0], fb[1], fb[2], fb[3], fb[4], msg);
        gather_k<<<(BB * NN * 4 + 255) / 256, 256, 0, stream>>>(msg, start, agg);
    } else {
        agg = (float*)(ws + MSG_OFF);
        hipMemsetAsync(agg, 0, (size_t)BB * NN * 16 * 4, stream);
        edge_mlp2<0><<<2048, 64, 0, stream>>>(
            rel, recv, nullptr, wfrag, fb[0], fb[1], fb[2], fb[3], fb[4], agg);
    }

    node_mlp_r<<<1024, 64, 0, stream>>>(
        dyn, agg, wfrag, db[0], db[1], db[2], db[3], db[4], (float*)d_out);
}